// Round 3
// baseline (135.826 us; speedup 1.0000x reference)
//
#include <hip/hip_runtime.h>
#include <math.h>

// Problem constants (fixed by setup_inputs): B=8, H=W=64, N=128
#define BB 8
#define HH 64
#define WW 64
#define NN 128
#define CC (HH*WW)   // 4096

__device__ __forceinline__ float sqf(float x){ return x*x; }

// Sum across the 64 lanes of the first wave (all lanes get the result).
__device__ __forceinline__ float wsum64(float v){
#pragma unroll
  for (int k = 1; k < 64; k <<= 1) v += __shfl_xor(v, k, 64);
  return v;
}

// ws layout (floats): sums[16]: [dir*8 + b] = sum over n of (S - 2D + T)

__global__ void lpml_zero(float* __restrict__ sums){
  if (threadIdx.x < 16) sums[threadIdx.x] = 0.f;
}

// Target prob-map value at one bin of the 6x6 window around (ty,tx).
// lane in [0,36) owns bin (r,c); returns val and bin coords.
__device__ __forceinline__ void target_bin(
    float ty, float tx, const float* k1d, int lane,
    float& val, int& by, int& bx, bool& inb)
{
  const float fy = floorf(ty), cy = ceilf(ty);
  const float fx = floorf(tx), cx = ceilf(tx);
  // torch.pairwise_distance adds eps=1e-6 to the per-component difference
  const float d0 = sqrtf(sqf(fy-ty+1e-6f) + sqf(fx-tx+1e-6f));
  const float d1 = sqrtf(sqf(fy-ty+1e-6f) + sqf(cx-tx+1e-6f));
  const float d2 = sqrtf(sqf(cy-ty+1e-6f) + sqf(fx-tx+1e-6f));
  const float d3 = sqrtf(sqf(cy-ty+1e-6f) + sqf(cx-tx+1e-6f));
  const float sd = fmaxf(d0+d1+d2+d3, 1e-12f);
  const float t0 = d0/sd, t1 = d1/sd, t2 = d2/sd, t3 = d3/sd;
  const int ify = (int)fy, ifx = (int)fx;
  const int ddy = (int)cy - ify, ddx = (int)cx - ifx;  // 0 if coord integral
  const float loc00 = t0 + (ddx==0?t1:0.f) + (ddy==0?t2:0.f) + ((ddy==0&&ddx==0)?t3:0.f);
  const float loc01 = (ddx==1?t1:0.f) + ((ddy==0&&ddx==1)?t3:0.f);
  const float loc10 = (ddy==1?t2:0.f) + ((ddy==1&&ddx==0)?t3:0.f);
  const float loc11 = ((ddy==1&&ddx==1)?t3:0.f);

  val = 0.f; by = 0; bx = 0; inb = false;
  if (lane < 36) {
    const int r = lane / 6, c = lane % 6;
    by = ify - 2 + r; bx = ifx - 2 + c;
    inb = (by >= 0 && by < HH && bx >= 0 && bx < WW);
    if (inb) {
      const float kr0 = (r <= 4) ? k1d[r]   : 0.f;
      const float kr1 = (r >= 1) ? k1d[r-1] : 0.f;
      const float kc0 = (c <= 4) ? k1d[c]   : 0.f;
      const float kc1 = (c >= 1) ? k1d[c-1] : 0.f;
      val = loc00*kr0*kc0 + loc01*kr0*kc1 + loc10*kr1*kc0 + loc11*kr1*kc1;
    }
  }
}

// Fused kernel, grid = 2048, interleaved by block parity:
//   even blocks: stream dir-1 S  — (b, y1, xhalf): 32 planes coalesced
//                through LDS; 128 points gather 2x2 taps; v^2 accumulated.
//   odd blocks : per-point (b,n) — dir-0 S over 4 coalesced rows, both
//                target windows, norms and cross terms (wave-0 shfl reduce).
// Each block ends in one atomicAdd into sums[dir*8+b].
__global__ __launch_bounds__(256) void lpml_fused(
    const float* __restrict__ corr, const float* __restrict__ kp,
    float* __restrict__ sums)
{
  const int tid = threadIdx.x;
  const bool is_stream = (blockIdx.x & 1) == 0;
  const int idx = blockIdx.x >> 1;          // 0..1023 for both roles
  const int b = idx >> 7;
  const size_t bbase = (size_t)b * CC * CC;

  __shared__ float plane[2][CC];            // 32 KB
  __shared__ int   soff[NN][4];
  __shared__ float swt[NN][4];
  __shared__ float red[256];

  if (is_stream) {
    const int half = idx & 1;
    const int y1   = (idx >> 1) & (HH-1);

    if (tid < NN) {
      // kp layout (B,N,2,2): [b][n][comp][which]; which=1 -> pts2
      const float* kpp = kp + (size_t)(b*NN + tid)*4;
      const float sy = kpp[1], sx = kpp[3];
      const float y0f = floorf(sy), x0f = floorf(sx);
      const float wy = sy - y0f, wx = sx - x0f;
      int Y0 = (int)y0f; Y0 = Y0 < 0 ? 0 : (Y0 > HH-1 ? HH-1 : Y0);
      int X0 = (int)x0f; X0 = X0 < 0 ? 0 : (X0 > WW-1 ? WW-1 : X0);
      const int Y1 = (Y0+1 > HH-1) ? HH-1 : Y0+1;
      const int X1 = (X0+1 > WW-1) ? WW-1 : X0+1;
      soff[tid][0] = Y0*WW + X0; soff[tid][1] = Y0*WW + X1;
      soff[tid][2] = Y1*WW + X0; soff[tid][3] = Y1*WW + X1;
      swt[tid][0] = (1.f-wy)*(1.f-wx); swt[tid][1] = (1.f-wy)*wx;
      swt[tid][2] = wy*(1.f-wx);       swt[tid][3] = wy*wx;
    }
    __syncthreads();

    const int n = tid & (NN-1);
    const int g = tid >> 7;                 // which plane of the loaded pair
    const int o00 = soff[n][0], o01 = soff[n][1], o10 = soff[n][2], o11 = soff[n][3];
    const float w00 = swt[n][0], w01 = swt[n][1], w10 = swt[n][2], w11 = swt[n][3];

    const size_t rowbase = (((size_t)b*HH + y1)*WW + (size_t)half*32) * CC;
    float accv = 0.f;
    for (int it = 0; it < 16; ++it) {
      const float4* src = (const float4*)(corr + rowbase + (size_t)(2*it)*CC);
      float4* dst = (float4*)(&plane[0][0]);
#pragma unroll
      for (int k = 0; k < 8; ++k) dst[tid + 256*k] = src[tid + 256*k];
      __syncthreads();
      const float* P = &plane[g][0];
      const float v = w00*P[o00] + w01*P[o01] + w10*P[o10] + w11*P[o11];
      accv += v*v;
      __syncthreads();
    }

    red[tid] = accv; __syncthreads();
    for (int s = 128; s > 0; s >>= 1) { if (tid < s) red[tid] += red[tid+s]; __syncthreads(); }
    if (tid == 0) atomicAdd(&sums[8 + b], red[0]);

  } else {
    const int n = idx & 127;
    const float* kpp = kp + (size_t)(b*NN + n)*4;
    const float p1y = kpp[0], p2y = kpp[1], p1x = kpp[2], p2x = kpp[3];

    // bilinear taps from pts1 -> 4 channel rows in (y1,x1) space (dir-0 pred)
    const float y0fa = floorf(p1y), x0fa = floorf(p1x);
    const float wya = p1y - y0fa, wxa = p1x - x0fa;
    int Y0a = (int)y0fa; Y0a = Y0a < 0 ? 0 : (Y0a > HH-1 ? HH-1 : Y0a);
    int X0a = (int)x0fa; X0a = X0a < 0 ? 0 : (X0a > WW-1 ? WW-1 : X0a);
    const int Y1a = (Y0a+1 > HH-1) ? HH-1 : Y0a+1;
    const int X1a = (X0a+1 > WW-1) ? WW-1 : X0a+1;
    const float w00a = (1.f-wya)*(1.f-wxa), w01a = (1.f-wya)*wxa;
    const float w10a = wya*(1.f-wxa),       w11a = wya*wxa;
    const float* r00 = corr + bbase + (size_t)(Y0a*WW + X0a) * CC;
    const float* r01 = corr + bbase + (size_t)(Y0a*WW + X1a) * CC;
    const float* r10 = corr + bbase + (size_t)(Y1a*WW + X0a) * CC;
    const float* r11 = corr + bbase + (size_t)(Y1a*WW + X1a) * CC;

    // bilinear taps from pts2 -> in-plane offsets (dir-1 pred)
    const float y0fb = floorf(p2y), x0fb = floorf(p2x);
    const float wyb = p2y - y0fb, wxb = p2x - x0fb;
    int Y0b = (int)y0fb; Y0b = Y0b < 0 ? 0 : (Y0b > HH-1 ? HH-1 : Y0b);
    int X0b = (int)x0fb; X0b = X0b < 0 ? 0 : (X0b > WW-1 ? WW-1 : X0b);
    const int Y1b = (Y0b+1 > HH-1) ? HH-1 : Y0b+1;
    const int X1b = (X0b+1 > WW-1) ? WW-1 : X0b+1;
    const float w00b = (1.f-wyb)*(1.f-wxb), w01b = (1.f-wyb)*wxb;
    const float w10b = wyb*(1.f-wxb),       w11b = wyb*wxb;
    const int o00b = Y0b*WW + X0b, o01b = Y0b*WW + X1b;
    const int o10b = Y1b*WW + X0b, o11b = Y1b*WW + X1b;

    // ---- S0 = sum_c pred12^2 over 4096 channels (coalesced float4) ----
    float ss = 0.f;
    for (int c0 = tid*4; c0 < CC; c0 += 1024) {
      const float4 a  = *(const float4*)(r00 + c0);
      const float4 bq = *(const float4*)(r01 + c0);
      const float4 cq = *(const float4*)(r10 + c0);
      const float4 dq = *(const float4*)(r11 + c0);
      const float p0 = w00a*a.x + w01a*bq.x + w10a*cq.x + w11a*dq.x;
      const float p1 = w00a*a.y + w01a*bq.y + w10a*cq.y + w11a*dq.y;
      const float p2 = w00a*a.z + w01a*bq.z + w10a*cq.z + w11a*dq.z;
      const float p3 = w00a*a.w + w01a*bq.w + w10a*cq.w + w11a*dq.w;
      ss += p0*p0 + p1*p1 + p2*p2 + p3*p3;
    }
    red[tid] = ss; __syncthreads();
    for (int s = 128; s > 0; s >>= 1) { if (tid < s) red[tid] += red[tid+s]; __syncthreads(); }
    const float S0 = red[0];

    // ---- targets + cross terms: single wave, shfl reductions ----
    if (tid < 64) {
      float k1d[5];
      {
        float ksum = 0.f;
#pragma unroll
        for (int i = 0; i < 5; ++i) { const float d = (float)(i-2); k1d[i] = expf(-d*d*1.125f); ksum += k1d[i]; }
#pragma unroll
        for (int i = 0; i < 5; ++i) k1d[i] /= ksum;
      }

      // dir 0: target at pts2 (channels = (y2,x2) bins)
      float tot0;
      {
        float val; int by, bx; bool inb;
        target_bin(p2y, p2x, k1d, tid, val, by, bx, inb);
        const float nrm2 = wsum64(inb ? val*val : 0.f);
        const float nrmc = fmaxf(sqrtf(nrm2), 1e-12f);
        const float T = nrm2 / (nrmc*nrmc);
        float dc = 0.f;
        if (inb) {
          const int cbin = by*WW + bx;
          const float predbin = w00a*r00[cbin] + w01a*r01[cbin]
                              + w10a*r10[cbin] + w11a*r11[cbin];
          dc = (val / nrmc) * predbin;
        }
        const float D = wsum64(dc);
        tot0 = S0 - 2.f*D + T;
      }
      // dir 1: target at pts1 (channels = (y1,x1) bins)
      float tot1;
      {
        float val; int by, bx; bool inb;
        target_bin(p1y, p1x, k1d, tid, val, by, bx, inb);
        const float nrm2 = wsum64(inb ? val*val : 0.f);
        const float nrmc = fmaxf(sqrtf(nrm2), 1e-12f);
        const float T = nrm2 / (nrmc*nrmc);
        float dc = 0.f;
        if (inb) {
          const float* slab = corr + bbase + (size_t)(by*WW + bx) * CC;
          const float predbin = w00b*slab[o00b] + w01b*slab[o01b]
                              + w10b*slab[o10b] + w11b*slab[o11b];
          dc = (val / nrmc) * predbin;
        }
        const float D = wsum64(dc);
        tot1 = -2.f*D + T;
      }
      if (tid == 0) {
        atomicAdd(&sums[b],     tot0);
        atomicAdd(&sums[8 + b], tot1);
      }
    }
  }
}

// loss = mean_b sqrt(sums[b]) + mean_b sqrt(sums[8+b])
__global__ void lpml_reduce(const float* __restrict__ sums, float* __restrict__ out)
{
  if (threadIdx.x == 0) {
    float l = 0.f;
#pragma unroll
    for (int b = 0; b < BB; ++b) l += sqrtf(sums[b]) + sqrtf(sums[8 + b]);
    out[0] = l / (float)BB;
  }
}

extern "C" void kernel_launch(void* const* d_in, const int* in_sizes, int n_in,
                              void* d_out, int out_size, void* d_ws, size_t ws_size,
                              hipStream_t stream) {
  const float* corr = (const float*)d_in[0];  // (B,H,W,H,W) f32
  const float* kp   = (const float*)d_in[1];  // (B,N,2,2) f32
  float* sums = (float*)d_ws;                 // 16 floats

  hipLaunchKernelGGL(lpml_zero,  dim3(1),    dim3(64),  0, stream, sums);
  hipLaunchKernelGGL(lpml_fused, dim3(2048), dim3(256), 0, stream, corr, kp, sums);
  hipLaunchKernelGGL(lpml_reduce, dim3(1),   dim3(64),  0, stream, sums, (float*)d_out);
}

// Round 5
// 104.063 us; speedup vs baseline: 1.3052x; 1.3052x over previous
//
#include <hip/hip_runtime.h>
#include <math.h>

// Problem constants (fixed by setup_inputs): B=8, H=W=64, N=128
#define BB 8
#define HH 64
#define WW 64
#define NN 128
#define CC (HH*WW)   // 4096

__device__ __forceinline__ float sqf(float x){ return x*x; }

// Sum across the 64 lanes of a wave (all lanes get the result).
__device__ __forceinline__ float wsum64(float v){
#pragma unroll
  for (int k = 1; k < 64; k <<= 1) v += __shfl_xor(v, k, 64);
  return v;
}

// Target prob-map value at one bin of the 6x6 window around (ty,tx).
// lane in [0,36) owns bin (r,c); returns val and bin coords.
__device__ __forceinline__ void target_bin(
    float ty, float tx, const float* k1d, int lane,
    float& val, int& by, int& bx, bool& inb)
{
  const float fy = floorf(ty), cy = ceilf(ty);
  const float fx = floorf(tx), cx = ceilf(tx);
  // torch.pairwise_distance adds eps=1e-6 to the per-component difference
  const float d0 = sqrtf(sqf(fy-ty+1e-6f) + sqf(fx-tx+1e-6f));
  const float d1 = sqrtf(sqf(fy-ty+1e-6f) + sqf(cx-tx+1e-6f));
  const float d2 = sqrtf(sqf(cy-ty+1e-6f) + sqf(fx-tx+1e-6f));
  const float d3 = sqrtf(sqf(cy-ty+1e-6f) + sqf(cx-tx+1e-6f));
  const float sd = fmaxf(d0+d1+d2+d3, 1e-12f);
  const float t0 = d0/sd, t1 = d1/sd, t2 = d2/sd, t3 = d3/sd;
  const int ify = (int)fy, ifx = (int)fx;
  const int ddy = (int)cy - ify, ddx = (int)cx - ifx;  // 0 if coord integral
  const float loc00 = t0 + (ddx==0?t1:0.f) + (ddy==0?t2:0.f) + ((ddy==0&&ddx==0)?t3:0.f);
  const float loc01 = (ddx==1?t1:0.f) + ((ddy==0&&ddx==1)?t3:0.f);
  const float loc10 = (ddy==1?t2:0.f) + ((ddy==1&&ddx==0)?t3:0.f);
  const float loc11 = ((ddy==1&&ddx==1)?t3:0.f);

  val = 0.f; by = 0; bx = 0; inb = false;
  if (lane < 36) {
    const int r = lane / 6, c = lane % 6;
    by = ify - 2 + r; bx = ifx - 2 + c;
    inb = (by >= 0 && by < HH && bx >= 0 && bx < WW);
    if (inb) {
      const float kr0 = (r <= 4) ? k1d[r]   : 0.f;
      const float kr1 = (r >= 1) ? k1d[r-1] : 0.f;
      const float kc0 = (c <= 4) ? k1d[c]   : 0.f;
      const float kc1 = (c >= 1) ? k1d[c-1] : 0.f;
      val = loc00*kr0*kc0 + loc01*kr0*kc1 + loc10*kr1*kc0 + loc11*kr1*kc1;
    }
  }
}

// Async global->LDS stage of one 16KB plane (4096 floats):
// 4 chunks x (256 threads x 16B) = 4 x 4KB.  Chunk k covers float4 indices
// [k*256, k*256+256); lane-ordered contiguous LDS dest per wave as required
// by global_load_lds (wave-uniform base + lane*16B).
__device__ __forceinline__ void issue_plane(const float* __restrict__ src,
                                            float4* dst, int tid)
{
#pragma unroll
  for (int k = 0; k < 4; ++k) {
    __builtin_amdgcn_global_load_lds(
        (const __attribute__((address_space(1))) void*)(src + (size_t)k*1024 + (size_t)tid*4),
        (__attribute__((address_space(3))) void*)(dst + (k*256 + tid)),
        16, 0, 0);
  }
}

// ws layout (floats): sblk[1024] stream per-block dir-1 partials;
//                     pblk0[1024], pblk1[1024] per-point totals (dir0/dir1).
// Every slot is written every call (no zero kernel, no atomics).

// Fused kernel, grid = 2048, APPENDED roles (not interleaved):
//   blocks 0..1023    : stream dir-1 S — (b, y1, xhalf): 32 planes, async
//                       double-buffered through LDS; 128 points gather taps.
//   blocks 1024..2047 : per-point (b,n) — dir-0 S over 4 coalesced rows,
//                       both target windows + norms + cross terms.
__global__ __launch_bounds__(256) void lpml_fused(
    const float* __restrict__ corr, const float* __restrict__ kp,
    float* __restrict__ sblk, float* __restrict__ pblk0,
    float* __restrict__ pblk1)
{
  const int tid = threadIdx.x;
  const int bi  = blockIdx.x;

  __shared__ float4 bufs[2][1024];     // 2 x 16KB plane double-buffer
  __shared__ int    soff[NN][4];
  __shared__ float  swt[NN][4];
  __shared__ float  red[256];

  if (bi < 1024) {
    // ---------------- stream role ----------------
    const int idx  = bi;
    const int b    = idx >> 7;
    const int y1   = (idx >> 1) & (HH-1);
    const int half = idx & 1;

    if (tid < NN) {
      // kp layout (B,N,2,2): [b][n][comp][which]; which=1 -> pts2
      const float* kpp = kp + (size_t)(b*NN + tid)*4;
      const float sy = kpp[1], sx = kpp[3];
      const float y0f = floorf(sy), x0f = floorf(sx);
      const float wy = sy - y0f, wx = sx - x0f;
      int Y0 = (int)y0f; Y0 = Y0 < 0 ? 0 : (Y0 > HH-1 ? HH-1 : Y0);
      int X0 = (int)x0f; X0 = X0 < 0 ? 0 : (X0 > WW-1 ? WW-1 : X0);
      const int Y1 = (Y0+1 > HH-1) ? HH-1 : Y0+1;
      const int X1 = (X0+1 > WW-1) ? WW-1 : X0+1;
      soff[tid][0] = Y0*WW + X0; soff[tid][1] = Y0*WW + X1;
      soff[tid][2] = Y1*WW + X0; soff[tid][3] = Y1*WW + X1;
      swt[tid][0] = (1.f-wy)*(1.f-wx); swt[tid][1] = (1.f-wy)*wx;
      swt[tid][2] = wy*(1.f-wx);       swt[tid][3] = wy*wx;
    }

    const size_t rowbase = (((size_t)b*HH + y1)*WW + (size_t)half*32) * CC;
    issue_plane(corr + rowbase, &bufs[0][0], tid);   // prologue: plane 0
    __syncthreads();                                  // drains vmcnt before barrier

    const int n = tid & (NN-1);
    const int o00 = soff[n][0], o01 = soff[n][1], o10 = soff[n][2], o11 = soff[n][3];
    const float w00 = swt[n][0], w01 = swt[n][1], w10 = swt[n][2], w11 = swt[n][3];

    float accv = 0.f;
    for (int p = 0; p < 32; ++p) {
      const int cur = p & 1;
      if (p + 1 < 32)
        issue_plane(corr + rowbase + (size_t)(p+1)*CC, &bufs[cur^1][0], tid);
      if (tid < NN) {
        const float* P = (const float*)&bufs[cur][0];
        const float v = w00*P[o00] + w01*P[o01] + w10*P[o10] + w11*P[o11];
        accv += v*v;
      }
      __syncthreads();   // vmcnt(0) drained here -> next plane ready
    }

    red[tid] = accv; __syncthreads();
    for (int s = 128; s > 0; s >>= 1) { if (tid < s) red[tid] += red[tid+s]; __syncthreads(); }
    if (tid == 0) sblk[idx] = red[0];

  } else {
    // ---------------- per-point role ----------------
    const int idx = bi - 1024;
    const int b   = idx >> 7;
    const int n   = idx & 127;
    const size_t bbase = (size_t)b * CC * CC;

    const float* kpp = kp + (size_t)(b*NN + n)*4;
    const float p1y = kpp[0], p2y = kpp[1], p1x = kpp[2], p2x = kpp[3];

    // bilinear taps from pts1 -> 4 channel rows (dir-0 pred)
    const float y0fa = floorf(p1y), x0fa = floorf(p1x);
    const float wya = p1y - y0fa, wxa = p1x - x0fa;
    int Y0a = (int)y0fa; Y0a = Y0a < 0 ? 0 : (Y0a > HH-1 ? HH-1 : Y0a);
    int X0a = (int)x0fa; X0a = X0a < 0 ? 0 : (X0a > WW-1 ? WW-1 : X0a);
    const int Y1a = (Y0a+1 > HH-1) ? HH-1 : Y0a+1;
    const int X1a = (X0a+1 > WW-1) ? WW-1 : X0a+1;
    const float w00a = (1.f-wya)*(1.f-wxa), w01a = (1.f-wya)*wxa;
    const float w10a = wya*(1.f-wxa),       w11a = wya*wxa;
    const float* r00 = corr + bbase + (size_t)(Y0a*WW + X0a) * CC;
    const float* r01 = corr + bbase + (size_t)(Y0a*WW + X1a) * CC;
    const float* r10 = corr + bbase + (size_t)(Y1a*WW + X0a) * CC;
    const float* r11 = corr + bbase + (size_t)(Y1a*WW + X1a) * CC;

    // bilinear taps from pts2 -> in-plane offsets (dir-1 pred)
    const float y0fb = floorf(p2y), x0fb = floorf(p2x);
    const float wyb = p2y - y0fb, wxb = p2x - x0fb;
    int Y0b = (int)y0fb; Y0b = Y0b < 0 ? 0 : (Y0b > HH-1 ? HH-1 : Y0b);
    int X0b = (int)x0fb; X0b = X0b < 0 ? 0 : (X0b > WW-1 ? WW-1 : X0b);
    const int Y1b = (Y0b+1 > HH-1) ? HH-1 : Y0b+1;
    const int X1b = (X0b+1 > WW-1) ? WW-1 : X0b+1;
    const float w00b = (1.f-wyb)*(1.f-wxb), w01b = (1.f-wyb)*wxb;
    const float w10b = wyb*(1.f-wxb),       w11b = wyb*wxb;
    const int o00b = Y0b*WW + X0b, o01b = Y0b*WW + X1b;
    const int o10b = Y1b*WW + X0b, o11b = Y1b*WW + X1b;

    // ---- S0 = sum_c pred12^2 over 4096 channels (coalesced float4) ----
    float ss = 0.f;
    for (int c0 = tid*4; c0 < CC; c0 += 1024) {
      const float4 a  = *(const float4*)(r00 + c0);
      const float4 bq = *(const float4*)(r01 + c0);
      const float4 cq = *(const float4*)(r10 + c0);
      const float4 dq = *(const float4*)(r11 + c0);
      const float p0 = w00a*a.x + w01a*bq.x + w10a*cq.x + w11a*dq.x;
      const float p1 = w00a*a.y + w01a*bq.y + w10a*cq.y + w11a*dq.y;
      const float p2 = w00a*a.z + w01a*bq.z + w10a*cq.z + w11a*dq.z;
      const float p3 = w00a*a.w + w01a*bq.w + w10a*cq.w + w11a*dq.w;
      ss += p0*p0 + p1*p1 + p2*p2 + p3*p3;
    }
    red[tid] = ss; __syncthreads();
    for (int s = 128; s > 0; s >>= 1) { if (tid < s) red[tid] += red[tid+s]; __syncthreads(); }
    const float S0 = red[0];

    // ---- targets + cross terms: single wave, shfl reductions ----
    if (tid < 64) {
      float k1d[5];
      {
        float ksum = 0.f;
#pragma unroll
        for (int i = 0; i < 5; ++i) { const float d = (float)(i-2); k1d[i] = expf(-d*d*1.125f); ksum += k1d[i]; }
#pragma unroll
        for (int i = 0; i < 5; ++i) k1d[i] /= ksum;
      }

      // dir 0: target at pts2 (channels = (y2,x2) bins)
      {
        float val; int by, bx; bool inb;
        target_bin(p2y, p2x, k1d, tid, val, by, bx, inb);
        const float nrm2 = wsum64(inb ? val*val : 0.f);
        const float nrmc = fmaxf(sqrtf(nrm2), 1e-12f);
        const float T = nrm2 / (nrmc*nrmc);
        float dc = 0.f;
        if (inb) {
          const int cbin = by*WW + bx;
          const float predbin = w00a*r00[cbin] + w01a*r01[cbin]
                              + w10a*r10[cbin] + w11a*r11[cbin];
          dc = (val / nrmc) * predbin;
        }
        const float D = wsum64(dc);
        if (tid == 0) pblk0[idx] = S0 - 2.f*D + T;
      }
      // dir 1: target at pts1 (channels = (y1,x1) bins)
      {
        float val; int by, bx; bool inb;
        target_bin(p1y, p1x, k1d, tid, val, by, bx, inb);
        const float nrm2 = wsum64(inb ? val*val : 0.f);
        const float nrmc = fmaxf(sqrtf(nrm2), 1e-12f);
        const float T = nrm2 / (nrmc*nrmc);
        float dc = 0.f;
        if (inb) {
          const float* slab = corr + bbase + (size_t)(by*WW + bx) * CC;
          const float predbin = w00b*slab[o00b] + w01b*slab[o01b]
                              + w10b*slab[o10b] + w11b*slab[o11b];
          dc = (val / nrmc) * predbin;
        }
        const float D = wsum64(dc);
        if (tid == 0) pblk1[idx] = -2.f*D + T;
      }
    }
  }
}

// loss = mean_b sqrt(sum_n dir0) + mean_b sqrt(sum_n dir1 + streamed S)
__global__ __launch_bounds__(256) void lpml_reduce(
    const float* __restrict__ sblk, const float* __restrict__ pblk0,
    const float* __restrict__ pblk1, float* __restrict__ out)
{
  __shared__ float sh[16];
  const int t   = threadIdx.x;        // 256 threads
  const int grp = t >> 4;             // 0..15 -> (dir,b)
  const int sub = t & 15;
  const int dir = grp >> 3, b = grp & 7;
  float s = 0.f;
  for (int i = sub; i < NN; i += 16) {
    const int j = b*NN + i;
    s += dir ? (pblk1[j] + sblk[j]) : pblk0[j];
  }
#pragma unroll
  for (int k = 1; k < 16; k <<= 1) s += __shfl_xor(s, k, 64);
  if (sub == 0) sh[grp] = sqrtf(s);
  __syncthreads();
  if (t == 0) {
    float l = 0.f;
#pragma unroll
    for (int i = 0; i < 16; ++i) l += sh[i];
    out[0] = l / (float)BB;
  }
}

extern "C" void kernel_launch(void* const* d_in, const int* in_sizes, int n_in,
                              void* d_out, int out_size, void* d_ws, size_t ws_size,
                              hipStream_t stream) {
  const float* corr = (const float*)d_in[0];  // (B,H,W,H,W) f32
  const float* kp   = (const float*)d_in[1];  // (B,N,2,2) f32
  float* sblk  = (float*)d_ws;                // [0,1024)
  float* pblk0 = (float*)d_ws + 1024;         // [1024,2048)
  float* pblk1 = (float*)d_ws + 2048;         // [2048,3072)

  hipLaunchKernelGGL(lpml_fused, dim3(2048), dim3(256), 0, stream,
                     corr, kp, sblk, pblk0, pblk1);
  hipLaunchKernelGGL(lpml_reduce, dim3(1), dim3(256), 0, stream,
                     sblk, pblk0, pblk1, (float*)d_out);
}